// Round 3
// baseline (37051.294 us; speedup 1.0000x reference)
//
#include <hip/hip_runtime.h>
#include <math.h>

// ---------------------------------------------------------------------------
// VQ-VAE forward, fp32, workspace = 2 x 128 MiB of d_ws.
// R3 change vs R2: occupancy fix for direct convs.
//   conv3x3: CI_T 8->4  (LDS 43.5 -> 22.8 KB), __launch_bounds__(256,4)
//   conv4x4s2: CI_T 2->1 (LDS 37.9 -> 18.7 KB), __launch_bounds__(256,4)
//   convT: __launch_bounds__(256,4)
// Theory: R2 counters showed VALUBusy 34% / Occupancy 12% (VGPR=132 + LDS both
// cap ~3 blocks/CU) -> latency-bound. 4 blocks/CU should lift VALUBusy ~2x.
// ---------------------------------------------------------------------------

#define RE_SIZE 786432

// ---------------- conv 1x1 (+bias, ACT: 0=none, 2=sigmoid) ----------------
template<int ACT, int CW>
__global__ __launch_bounds__(256) void conv1x1_kernel(
    const float* __restrict__ in, const float* __restrict__ w,
    const float* __restrict__ bias, float* __restrict__ out,
    int N, int Cin, int Cout, int HW) {
  extern __shared__ float wl[];                   // CW * Cin
  int co0 = blockIdx.y * CW;
  for (int i = threadIdx.x; i < CW * Cin; i += blockDim.x)
    wl[i] = w[(long)co0 * Cin + i];
  __syncthreads();
  int HW4 = HW >> 2;
  long p4 = (long)blockIdx.x * blockDim.x + threadIdx.x;
  if (p4 >= (long)N * HW4) return;
  int n = (int)(p4 / HW4), hw4 = (int)(p4 % HW4);
  const float4* inp = (const float4*)(in + (long)n * Cin * HW) + hw4;
  float4* outp = (float4*)(out + (long)n * Cout * HW) + hw4;
  float4 acc[CW];
#pragma unroll
  for (int j = 0; j < CW; ++j) { float bb = bias[co0 + j]; acc[j] = make_float4(bb, bb, bb, bb); }
  for (int ci = 0; ci < Cin; ++ci) {
    float4 v = inp[(long)ci * HW4];
#pragma unroll
    for (int j = 0; j < CW; ++j) {
      float ww = wl[j * Cin + ci];
      acc[j].x = fmaf(ww, v.x, acc[j].x);
      acc[j].y = fmaf(ww, v.y, acc[j].y);
      acc[j].z = fmaf(ww, v.z, acc[j].z);
      acc[j].w = fmaf(ww, v.w, acc[j].w);
    }
  }
#pragma unroll
  for (int j = 0; j < CW; ++j) {
    float4 v = acc[j];
    if (ACT == 2) {
      v.x = 1.f / (1.f + expf(-v.x));
      v.y = 1.f / (1.f + expf(-v.y));
      v.z = 1.f / (1.f + expf(-v.z));
      v.w = 1.f / (1.f + expf(-v.w));
    }
    outp[(long)(co0 + j) * HW4] = v;
  }
}

// ---------------- conv 3x3 s1 p1, 128->128, +bias ---------------------------
// IMODE: 0 = raw input; 1 = bn+relu fused on staged input; 2 = input is
// enc_in(x) computed on the fly (1x1 conv 3->128).
// Tile: 32x32 spatial, 16 out-ch per block. CI_T=4 => LDS 22.8 KB.
template<int IMODE>
__global__ __launch_bounds__(256, 4) void conv3x3_kernel(
    const float* __restrict__ in, const float* __restrict__ w,
    const float* __restrict__ bias, float* __restrict__ out,
    int H, int W, const float2* __restrict__ mr,
    const float* __restrict__ xin, const float* __restrict__ w1,
    const float* __restrict__ b1) {
  constexpr int C = 128, CI_T = 4, CO_T = 16;
  __shared__ float s_in[CI_T][34][34];
  __shared__ float s_w[CO_T][CI_T][12];           // 9 taps padded to 12
  int tid = threadIdx.x;
  int tilesX = W >> 5;
  int ty0 = (blockIdx.x / tilesX) << 5;
  int tx0 = (blockIdx.x % tilesX) << 5;
  int co0 = blockIdx.y * CO_T;
  int n = blockIdx.z;
  int ty = tid >> 3, txg = (tid & 7) << 2;
  float acc[CO_T][4];
#pragma unroll
  for (int a = 0; a < CO_T; ++a) acc[a][0] = acc[a][1] = acc[a][2] = acc[a][3] = 0.f;
  const long HWl = (long)H * W;
  const long ibase = (long)n * C * HWl;
  for (int ci0 = 0; ci0 < C; ci0 += CI_T) {
    for (int l = tid; l < CI_T * 34 * 34; l += 256) {
      int ci = l / (34 * 34), rem = l % (34 * 34);
      int yy = rem / 34, xx = rem % 34;
      int gy = ty0 + yy - 1, gx = tx0 + xx - 1;
      float v = 0.f;
      if ((unsigned)gy < (unsigned)H && (unsigned)gx < (unsigned)W) {
        if (IMODE == 2) {
          int c = ci0 + ci;
          const float* xp = xin + (long)n * 3 * HWl + (long)gy * W + gx;
          v = b1[c];
          v = fmaf(w1[c * 3 + 0], xp[0], v);
          v = fmaf(w1[c * 3 + 1], xp[HWl], v);
          v = fmaf(w1[c * 3 + 2], xp[2 * HWl], v);
        } else {
          v = in[ibase + (long)(ci0 + ci) * HWl + (long)gy * W + gx];
          if (IMODE == 1) {
            float2 s = mr[ci0 + ci];
            v = fmaxf((v - s.x) * s.y, 0.f);
          }
        }
      }
      s_in[ci][yy][xx] = v;
    }
    for (int l = tid; l < CO_T * CI_T * 9; l += 256) {
      int co = l / (CI_T * 9), rem = l % (CI_T * 9);
      int ci = rem / 9, k = rem % 9;
      s_w[co][ci][k] = w[((long)(co0 + co) * C + ci0 + ci) * 9 + k];
    }
    __syncthreads();
#pragma unroll
    for (int ci = 0; ci < CI_T; ++ci) {
      float r[3][6];
#pragma unroll
      for (int dy = 0; dy < 3; ++dy)
#pragma unroll
        for (int dx = 0; dx < 6; ++dx)
          r[dy][dx] = s_in[ci][ty + dy][txg + dx];
#pragma unroll
      for (int co = 0; co < CO_T; ++co) {
        const float* wp = s_w[co][ci];
        float4 w0 = *(const float4*)wp;
        float4 w4 = *(const float4*)(wp + 4);
        float w8 = wp[8];
#pragma unroll
        for (int sp = 0; sp < 4; ++sp) {
          float a = acc[co][sp];
          a = fmaf(w0.x, r[0][sp], a);
          a = fmaf(w0.y, r[0][sp + 1], a);
          a = fmaf(w0.z, r[0][sp + 2], a);
          a = fmaf(w0.w, r[1][sp], a);
          a = fmaf(w4.x, r[1][sp + 1], a);
          a = fmaf(w4.y, r[1][sp + 2], a);
          a = fmaf(w4.z, r[2][sp], a);
          a = fmaf(w4.w, r[2][sp + 1], a);
          a = fmaf(w8,   r[2][sp + 2], a);
          acc[co][sp] = a;
        }
      }
    }
    __syncthreads();
  }
  int oy = ty0 + ty, ox = tx0 + txg;
#pragma unroll
  for (int co = 0; co < CO_T; ++co) {
    float bb = bias[co0 + co];
    float4 v = make_float4(acc[co][0] + bb, acc[co][1] + bb, acc[co][2] + bb, acc[co][3] + bb);
    *(float4*)(out + ibase + ((long)(co0 + co) * H + oy) * W + ox) = v;
  }
}

// ---------------- conv 4x4 s2 p1, 128->128, +bias +relu ---------------------
// CI_T=1 => LDS 18.7 KB.
__global__ __launch_bounds__(256, 4) void conv4x4s2_kernel(
    const float* __restrict__ in, const float* __restrict__ w,
    const float* __restrict__ bias, float* __restrict__ out,
    int Hin, int Win) {
  constexpr int C = 128, CO_T = 16;
  int Hout = Hin >> 1, Wout = Win >> 1;
  __shared__ float s_in[34][130];
  __shared__ float s_w[CO_T][16];
  int tid = threadIdx.x;
  int tilesX = Wout >> 6;
  int oy0 = (blockIdx.x / tilesX) << 4;
  int ox0 = (blockIdx.x % tilesX) << 6;
  int co0 = blockIdx.y * CO_T;
  int n = blockIdx.z;
  int ty = tid >> 4, txg = tid & 15;
  float acc[CO_T][4];
#pragma unroll
  for (int a = 0; a < CO_T; ++a) acc[a][0] = acc[a][1] = acc[a][2] = acc[a][3] = 0.f;
  const long ibase = (long)n * C * Hin * Win;
  int iy0 = 2 * oy0 - 1, ix0 = 2 * ox0 - 1;
  for (int ci = 0; ci < C; ++ci) {
    for (int l = tid; l < 34 * 130; l += 256) {
      int yy = l / 130, xx = l % 130;
      int gy = iy0 + yy, gx = ix0 + xx;
      float v = 0.f;
      if ((unsigned)gy < (unsigned)Hin && (unsigned)gx < (unsigned)Win)
        v = in[ibase + ((long)ci * Hin + gy) * Win + gx];
      s_in[yy][xx] = v;
    }
    if (tid < CO_T * 16) {
      int co = tid >> 4, k = tid & 15;
      s_w[co][k] = w[((long)(co0 + co) * C + ci) * 16 + k];
    }
    __syncthreads();
    {
      float r[4][10];
      int yb = ty << 1, xb = txg << 3;
#pragma unroll
      for (int dy = 0; dy < 4; ++dy)
#pragma unroll
        for (int dx = 0; dx < 10; ++dx)
          r[dy][dx] = s_in[yb + dy][xb + dx];
#pragma unroll
      for (int co = 0; co < CO_T; ++co) {
        const float* wp = s_w[co];
        float4 w0 = *(const float4*)wp;
        float4 w1 = *(const float4*)(wp + 4);
        float4 w2 = *(const float4*)(wp + 8);
        float4 w3 = *(const float4*)(wp + 12);
#pragma unroll
        for (int sp = 0; sp < 4; ++sp) {
          int xo = sp << 1;
          float a = acc[co][sp];
          a = fmaf(w0.x, r[0][xo], a);     a = fmaf(w0.y, r[0][xo + 1], a);
          a = fmaf(w0.z, r[0][xo + 2], a); a = fmaf(w0.w, r[0][xo + 3], a);
          a = fmaf(w1.x, r[1][xo], a);     a = fmaf(w1.y, r[1][xo + 1], a);
          a = fmaf(w1.z, r[1][xo + 2], a); a = fmaf(w1.w, r[1][xo + 3], a);
          a = fmaf(w2.x, r[2][xo], a);     a = fmaf(w2.y, r[2][xo + 1], a);
          a = fmaf(w2.z, r[2][xo + 2], a); a = fmaf(w2.w, r[2][xo + 3], a);
          a = fmaf(w3.x, r[3][xo], a);     a = fmaf(w3.y, r[3][xo + 1], a);
          a = fmaf(w3.z, r[3][xo + 2], a); a = fmaf(w3.w, r[3][xo + 3], a);
          acc[co][sp] = a;
        }
      }
    }
    __syncthreads();
  }
  const long obase = (long)n * C * Hout * Wout;
  int oy = oy0 + ty, oxb = ox0 + (txg << 2);
#pragma unroll
  for (int co = 0; co < CO_T; ++co) {
    float bb = bias[co0 + co];
    float4 v = make_float4(fmaxf(acc[co][0] + bb, 0.f), fmaxf(acc[co][1] + bb, 0.f),
                           fmaxf(acc[co][2] + bb, 0.f), fmaxf(acc[co][3] + bb, 0.f));
    *(float4*)(out + obase + ((long)(co0 + co) * Hout + oy) * Wout + oxb) = v;
  }
}

// ---------------- ConvTranspose2d(k=4,s=2,p=1), torch w (I,O,4,4), +relu ----
__global__ __launch_bounds__(256, 4) void convT4x4_kernel(
    const float* __restrict__ in, const float* __restrict__ w,
    const float* __restrict__ bias, float* __restrict__ out,
    int Hin, int Win) {
  constexpr int C = 128, CI_T = 4, CO_T = 16;
  int Hout = Hin << 1, Wout = Win << 1;
  __shared__ float s_in[CI_T][18][66];
  __shared__ float s_w[CO_T][CI_T][4];
  int tid = threadIdx.x;
  int cls = blockIdx.z & 3, n = blockIdx.z >> 2;
  int py = cls >> 1, px = cls & 1;
  int tilesX = Win >> 6;
  int m0 = (blockIdx.x / tilesX) << 4;
  int x0 = (blockIdx.x % tilesX) << 6;
  int co0 = blockIdx.y * CO_T;
  int ty = tid >> 4, txg = tid & 15;
  int ky0 = py ? 0 : 1, ky1 = py ? 2 : 3;
  int dy0 = py ? 1 : 0, dy1 = py ? 0 : -1;
  int kx0 = px ? 0 : 1, kx1 = px ? 2 : 3;
  int dxA = px ? 1 : 0, dxB = px ? 0 : -1;
  float acc[CO_T][4];
#pragma unroll
  for (int a = 0; a < CO_T; ++a) acc[a][0] = acc[a][1] = acc[a][2] = acc[a][3] = 0.f;
  const long ibase = (long)n * C * Hin * Win;
  for (int ci0 = 0; ci0 < C; ci0 += CI_T) {
    for (int l = tid; l < CI_T * 18 * 66; l += 256) {
      int ci = l / (18 * 66), rem = l % (18 * 66);
      int yy = rem / 66, xx = rem % 66;
      int gy = m0 - 1 + yy, gx = x0 - 1 + xx;
      float v = 0.f;
      if ((unsigned)gy < (unsigned)Hin && (unsigned)gx < (unsigned)Win)
        v = in[ibase + ((long)(ci0 + ci) * Hin + gy) * Win + gx];
      s_in[ci][yy][xx] = v;
    }
    {
      int l = tid;  // CO_T*CI_T*4 == 256 exactly
      int co = l >> 4, rem = l & 15, ci = rem >> 2, j = rem & 3;
      int ky = (j & 2) ? ky1 : ky0;
      int kx = (j & 1) ? kx1 : kx0;
      s_w[co][ci][j] = w[((long)(ci0 + ci) * C + (co0 + co)) * 16 + ky * 4 + kx];
    }
    __syncthreads();
#pragma unroll
    for (int ci = 0; ci < CI_T; ++ci) {
      float r0v[6], r1v[6];
#pragma unroll
      for (int c2 = 0; c2 < 6; ++c2) {
        r0v[c2] = s_in[ci][ty + 1 + dy0][txg * 4 + c2];
        r1v[c2] = s_in[ci][ty + 1 + dy1][txg * 4 + c2];
      }
#pragma unroll
      for (int co = 0; co < CO_T; ++co) {
        float4 wv = *(const float4*)s_w[co][ci];
#pragma unroll
        for (int sp = 0; sp < 4; ++sp) {
          float a = acc[co][sp];
          a = fmaf(wv.x, r0v[sp + 1 + dxA], a);
          a = fmaf(wv.y, r0v[sp + 1 + dxB], a);
          a = fmaf(wv.z, r1v[sp + 1 + dxA], a);
          a = fmaf(wv.w, r1v[sp + 1 + dxB], a);
          acc[co][sp] = a;
        }
      }
    }
    __syncthreads();
  }
  const long obase = (long)n * C * Hout * Wout;
  int oy = ((m0 + ty) << 1) + py;
#pragma unroll
  for (int co = 0; co < CO_T; ++co) {
    float bb = bias[co0 + co];
    long rowoff = obase + ((long)(co0 + co) * Hout + oy) * Wout;
#pragma unroll
    for (int sp = 0; sp < 4; ++sp) {
      int ox = ((x0 + txg * 4 + sp) << 1) + px;
      out[rowoff + ox] = fmaxf(acc[co][sp] + bb, 0.f);
    }
  }
}

// ---------------- BN batch stats: mean + rsqrt(var+eps) ---------------------
__global__ __launch_bounds__(256) void bn_stats_kernel(
    const float* __restrict__ x, float2* __restrict__ mr, int N, int C, int HW) {
  int c = blockIdx.x;
  double s = 0.0, ss = 0.0;
  int HW4 = HW >> 2;
  for (int n = 0; n < N; ++n) {
    const float4* xp = (const float4*)(x + ((long)n * C + c) * HW);
    for (int i = threadIdx.x; i < HW4; i += 256) {
      float4 v = xp[i];
      s  += (double)v.x + (double)v.y + (double)v.z + (double)v.w;
      ss += (double)v.x * v.x + (double)v.y * v.y + (double)v.z * v.z + (double)v.w * v.w;
    }
  }
  __shared__ double sh_s[256], sh_ss[256];
  sh_s[threadIdx.x] = s; sh_ss[threadIdx.x] = ss;
  __syncthreads();
  for (int off = 128; off > 0; off >>= 1) {
    if (threadIdx.x < off) { sh_s[threadIdx.x] += sh_s[threadIdx.x + off];
                             sh_ss[threadIdx.x] += sh_ss[threadIdx.x + off]; }
    __syncthreads();
  }
  if (threadIdx.x == 0) {
    double cnt = (double)N * HW;
    double m = sh_s[0] / cnt;
    double var = sh_ss[0] / cnt - m * m;
    mr[c] = make_float2((float)m, (float)(1.0 / sqrt(var + 1e-5)));
  }
}

// ---------------- in-place: y = relu(bn(y) + residual) ----------------------
template<int RMODE>
__global__ __launch_bounds__(256) void bn_res_relu_kernel(
    float* __restrict__ y, const float2* __restrict__ mr,
    const float* __restrict__ res,
    const float* __restrict__ xin, const float* __restrict__ w1,
    const float* __restrict__ b1, int HW4) {
  int nc = blockIdx.y;
  int c = nc & 127, n = nc >> 7;
  float2 s = mr[c];
  int i = blockIdx.x * blockDim.x + threadIdx.x;
  if (i >= HW4) return;
  long off = (long)nc * HW4 + i;
  float4 v = ((const float4*)y)[off];
  v.x = (v.x - s.x) * s.y; v.y = (v.y - s.x) * s.y;
  v.z = (v.z - s.x) * s.y; v.w = (v.w - s.x) * s.y;
  float4 r4;
  if (RMODE == 0) {
    r4 = ((const float4*)res)[off];
  } else {
    const float4* xp = (const float4*)(xin) + (long)n * 3 * HW4 + i;
    float4 x0 = xp[0], x1 = xp[HW4], x2 = xp[2 * HW4];
    float wa = w1[c * 3 + 0], wb = w1[c * 3 + 1], wc = w1[c * 3 + 2], bb = b1[c];
    r4.x = fmaf(wa, x0.x, fmaf(wb, x1.x, fmaf(wc, x2.x, bb)));
    r4.y = fmaf(wa, x0.y, fmaf(wb, x1.y, fmaf(wc, x2.y, bb)));
    r4.z = fmaf(wa, x0.z, fmaf(wb, x1.z, fmaf(wc, x2.z, bb)));
    r4.w = fmaf(wa, x0.w, fmaf(wb, x1.w, fmaf(wc, x2.w, bb)));
  }
  v.x = fmaxf(v.x + r4.x, 0.f); v.y = fmaxf(v.y + r4.y, 0.f);
  v.z = fmaxf(v.z + r4.z, 0.f); v.w = fmaxf(v.w + r4.w, 0.f);
  ((float4*)y)[off] = v;
}

// ---------------- VQ: argmin_k ||z - e_k||^2, idx + histogram ---------------
__global__ __launch_bounds__(256) void vq_kernel(
    const float* __restrict__ z, const float* __restrict__ cb,
    float* __restrict__ idx_out, float* __restrict__ counts, int HWl) {
  __shared__ float s_z[64][65];
  __shared__ float s_cb[64][64];
  __shared__ float s_bd[4][64];
  __shared__ int   s_bk[4][64];
  int tid = threadIdx.x;
  int r0 = blockIdx.x * 64;
  for (int l = tid; l < 64 * 64; l += 256) {
    int c = l >> 6, rs = l & 63;
    int r = r0 + rs;
    int n = r / HWl, rem = r % HWl;
    s_z[rs][c] = z[((long)(n * 64 + c)) * HWl + rem];
  }
  int row = tid & 63, cg = tid >> 6;
  float best = 3.4e38f; int bestk = 0;
  for (int k0 = 0; k0 < 1024; k0 += 64) {
    __syncthreads();
    for (int l = tid; l < 4096; l += 256)
      s_cb[l >> 6][l & 63] = cb[(long)(k0 + (l >> 6)) * 64 + (l & 63)];
    __syncthreads();
#pragma unroll
    for (int j = 0; j < 16; ++j) {
      int kk = cg * 16 + j;
      const float* zp = s_z[row];
      const float* cp = s_cb[kk];
      float d = 0.f;
#pragma unroll
      for (int c = 0; c < 64; ++c) {
        float t = zp[c] - cp[c];
        d = fmaf(t, t, d);
      }
      int k = k0 + kk;
      if (d < best) { best = d; bestk = k; }
    }
  }
  s_bd[cg][row] = best; s_bk[cg][row] = bestk;
  __syncthreads();
  if (tid < 64) {
    float bd = s_bd[0][tid]; int bk = s_bk[0][tid];
#pragma unroll
    for (int g = 1; g < 4; ++g) {
      float d2 = s_bd[g][tid]; int k2 = s_bk[g][tid];
      if (d2 < bd || (d2 == bd && k2 < bk)) { bd = d2; bk = k2; }
    }
    idx_out[r0 + tid] = (float)bk;
    atomicAdd(&counts[bk], 1.0f);
  }
}

// ---------------- zero small buffer ----------------------------------------
__global__ __launch_bounds__(256) void zero_kernel(float* __restrict__ p, int n) {
  int i = blockIdx.x * 256 + threadIdx.x;
  if (i < n) p[i] = 0.f;
}

// ---------------- loss = sum p log p  (= -entropy) --------------------------
__global__ __launch_bounds__(256) void entropy_kernel(
    const float* __restrict__ counts, float* __restrict__ loss_out) {
  __shared__ double sh[256];
  int tid = threadIdx.x;
  double s = 0.0;
  for (int i = tid; i < 1024; i += 256) s += (double)counts[i] + 1e-6;
  sh[tid] = s; __syncthreads();
  for (int off = 128; off > 0; off >>= 1) {
    if (tid < off) sh[tid] += sh[tid + off];
    __syncthreads();
  }
  double S = sh[0];
  __syncthreads();
  double pl = 0.0;
  for (int i = tid; i < 1024; i += 256) {
    double p = ((double)counts[i] + 1e-6) / S;
    pl += p * log(p);
  }
  sh[tid] = pl; __syncthreads();
  for (int off = 128; off > 0; off >>= 1) {
    if (tid < off) sh[tid] += sh[tid + off];
    __syncthreads();
  }
  if (tid == 0) loss_out[0] = (float)sh[0];
}

// ---------------------------------------------------------------------------
extern "C" void kernel_launch(void* const* d_in, const int* in_sizes, int n_in,
                              void* d_out, int out_size, void* d_ws, size_t ws_size,
                              hipStream_t stream) {
  (void)in_sizes; (void)n_in; (void)out_size; (void)ws_size;
  const float* x          = (const float*)d_in[0];
  const float* enc_in_w   = (const float*)d_in[1];
  const float* enc_in_b   = (const float*)d_in[2];
  const float* enc_res_w1 = (const float*)d_in[3];
  const float* enc_res_b1 = (const float*)d_in[4];
  const float* enc_res_w2 = (const float*)d_in[5];
  const float* enc_res_b2 = (const float*)d_in[6];
  const float* enc_down_w = (const float*)d_in[7];
  const float* enc_down_b = (const float*)d_in[8];
  const float* enc_out_w  = (const float*)d_in[9];
  const float* enc_out_b  = (const float*)d_in[10];
  const float* dec_in_w   = (const float*)d_in[11];
  const float* dec_in_b   = (const float*)d_in[12];
  const float* dec_res_w1 = (const float*)d_in[13];
  const float* dec_res_b1 = (const float*)d_in[14];
  const float* dec_res_w2 = (const float*)d_in[15];
  const float* dec_res_b2 = (const float*)d_in[16];
  const float* dec_up_w   = (const float*)d_in[17];
  const float* dec_up_b   = (const float*)d_in[18];
  const float* dec_out_w  = (const float*)d_in[19];
  const float* dec_out_b  = (const float*)d_in[20];
  const float* codebook   = (const float*)d_in[21];
  float* out = (float*)d_out;

  // Workspace: EXACTLY two 128-MiB fp32 buffers.
  const long BIG = 33554432;
  const long S1 = 8388608, S2 = 16777216, S3 = 25165824;
  float* P0 = (float*)d_ws;
  float* P1 = P0 + BIG;
  // Small scratch in d_out[0:1280) — recon overwrites it at the end.
  float2* mr  = (float2*)out;
  float* hist = out + 256;

  const int W3 = 128 * 128 * 9, W4 = 128 * 128 * 16, BS = 128;

  // ===================== encoder =====================
  conv3x3_kernel<2><<<dim3(64, 8, 4), 256, 0, stream>>>(
      nullptr, enc_res_w1, enc_res_b1, P0, 256, 256, nullptr, x, enc_in_w, enc_in_b);
  bn_stats_kernel<<<128, 256, 0, stream>>>(P0, mr, 4, 128, 65536);
  conv3x3_kernel<1><<<dim3(64, 8, 4), 256, 0, stream>>>(
      P0, enc_res_w2, enc_res_b2, P1, 256, 256, mr, nullptr, nullptr, nullptr);
  bn_stats_kernel<<<128, 256, 0, stream>>>(P1, mr, 4, 128, 65536);
  bn_res_relu_kernel<1><<<dim3(64, 512), 256, 0, stream>>>(
      P1, mr, nullptr, x, enc_in_w, enc_in_b, 16384);
  conv4x4s2_kernel<<<dim3(16, 8, 4), 256, 0, stream>>>(P1, enc_down_w, enc_down_b, P0, 256, 256);

  conv3x3_kernel<0><<<dim3(16, 8, 4), 256, 0, stream>>>(
      P0, enc_res_w1 + W3, enc_res_b1 + BS, P0 + S1, 128, 128, nullptr, nullptr, nullptr, nullptr);
  bn_stats_kernel<<<128, 256, 0, stream>>>(P0 + S1, mr, 4, 128, 16384);
  conv3x3_kernel<1><<<dim3(16, 8, 4), 256, 0, stream>>>(
      P0 + S1, enc_res_w2 + W3, enc_res_b2 + BS, P0 + S2, 128, 128, mr, nullptr, nullptr, nullptr);
  bn_stats_kernel<<<128, 256, 0, stream>>>(P0 + S2, mr, 4, 128, 16384);
  bn_res_relu_kernel<0><<<dim3(16, 512), 256, 0, stream>>>(
      P0 + S2, mr, P0, nullptr, nullptr, nullptr, 4096);
  conv4x4s2_kernel<<<dim3(4, 8, 4), 256, 0, stream>>>(
      P0 + S2, enc_down_w + W4, enc_down_b + BS, P0 + S3, 128, 128);

  conv1x1_kernel<0, 16><<<dim3(16, 4), 256, 16 * 128 * 4, stream>>>(
      P0 + S3, enc_out_w, enc_out_b, P1, 4, 128, 64, 4096);

  // ===================== VQ =====================
  zero_kernel<<<4, 256, 0, stream>>>(hist, 1024);
  vq_kernel<<<256, 256, 0, stream>>>(P1, codebook, out + RE_SIZE + 1, hist, 4096);
  entropy_kernel<<<1, 256, 0, stream>>>(hist, out + RE_SIZE);

  // ===================== decoder =====================
  conv1x1_kernel<0, 16><<<dim3(16, 8), 256, 16 * 64 * 4, stream>>>(
      P1, dec_in_w, dec_in_b, P0, 4, 64, 128, 4096);

  conv3x3_kernel<0><<<dim3(4, 8, 4), 256, 0, stream>>>(
      P0, dec_res_w1, dec_res_b1, P0 + S1, 64, 64, nullptr, nullptr, nullptr, nullptr);
  bn_stats_kernel<<<128, 256, 0, stream>>>(P0 + S1, mr, 4, 128, 4096);
  conv3x3_kernel<1><<<dim3(4, 8, 4), 256, 0, stream>>>(
      P0 + S1, dec_res_w2, dec_res_b2, P0 + S2, 64, 64, mr, nullptr, nullptr, nullptr);
  bn_stats_kernel<<<128, 256, 0, stream>>>(P0 + S2, mr, 4, 128, 4096);
  bn_res_relu_kernel<0><<<dim3(4, 512), 256, 0, stream>>>(
      P0 + S2, mr, P0, nullptr, nullptr, nullptr, 1024);
  convT4x4_kernel<<<dim3(4, 8, 16), 256, 0, stream>>>(P0 + S2, dec_up_w, dec_up_b, P0 + S3, 64, 64);

  conv3x3_kernel<0><<<dim3(16, 8, 4), 256, 0, stream>>>(
      P0 + S3, dec_res_w1 + W3, dec_res_b1 + BS, P1, 128, 128, nullptr, nullptr, nullptr, nullptr);
  bn_stats_kernel<<<128, 256, 0, stream>>>(P1, mr, 4, 128, 16384);
  conv3x3_kernel<1><<<dim3(16, 8, 4), 256, 0, stream>>>(
      P1, dec_res_w2 + W3, dec_res_b2 + BS, P1 + S1, 128, 128, mr, nullptr, nullptr, nullptr);
  bn_stats_kernel<<<128, 256, 0, stream>>>(P1 + S1, mr, 4, 128, 16384);
  bn_res_relu_kernel<0><<<dim3(16, 512), 256, 0, stream>>>(
      P1 + S1, mr, P0 + S3, nullptr, nullptr, nullptr, 4096);
  convT4x4_kernel<<<dim3(16, 8, 16), 256, 0, stream>>>(
      P1 + S1, dec_up_w + W4, dec_up_b + BS, P0, 128, 128);

  conv1x1_kernel<2, 3><<<dim3(256, 1), 256, 3 * 128 * 4, stream>>>(
      P0, dec_out_w, dec_out_b, out, 4, 128, 3, 65536);
}

// Round 4
// 11830.315 us; speedup vs baseline: 3.1319x; 3.1319x over previous
//
#include <hip/hip_runtime.h>
#include <math.h>

// ---------------------------------------------------------------------------
// VQ-VAE forward, fp32, workspace = 2 x 128 MiB of d_ws.
// R4 vs R2 (13.2 ms baseline): conv3x3 rebalanced for LDS-issue pressure.
//   R2 inner loop: 16 co x 4 px/thread -> 48 broadcast weight-reads per 576 FMA
//   R4 inner loop:  8 co x 8 px/thread -> 24 weight-reads + 9 input-reads per 576 FMA
//   (R3 lesson: NEVER cap VGPR below the accumulator working set -> spill disaster)
// conv4x4s2 / convT reverted to the R2-proven configs (no launch_bounds caps).
// ---------------------------------------------------------------------------

#define RE_SIZE 786432

// ---------------- conv 1x1 (+bias, ACT: 0=none, 2=sigmoid) ----------------
template<int ACT, int CW>
__global__ __launch_bounds__(256) void conv1x1_kernel(
    const float* __restrict__ in, const float* __restrict__ w,
    const float* __restrict__ bias, float* __restrict__ out,
    int N, int Cin, int Cout, int HW) {
  extern __shared__ float wl[];                   // CW * Cin
  int co0 = blockIdx.y * CW;
  for (int i = threadIdx.x; i < CW * Cin; i += blockDim.x)
    wl[i] = w[(long)co0 * Cin + i];
  __syncthreads();
  int HW4 = HW >> 2;
  long p4 = (long)blockIdx.x * blockDim.x + threadIdx.x;
  if (p4 >= (long)N * HW4) return;
  int n = (int)(p4 / HW4), hw4 = (int)(p4 % HW4);
  const float4* inp = (const float4*)(in + (long)n * Cin * HW) + hw4;
  float4* outp = (float4*)(out + (long)n * Cout * HW) + hw4;
  float4 acc[CW];
#pragma unroll
  for (int j = 0; j < CW; ++j) { float bb = bias[co0 + j]; acc[j] = make_float4(bb, bb, bb, bb); }
  for (int ci = 0; ci < Cin; ++ci) {
    float4 v = inp[(long)ci * HW4];
#pragma unroll
    for (int j = 0; j < CW; ++j) {
      float ww = wl[j * Cin + ci];
      acc[j].x = fmaf(ww, v.x, acc[j].x);
      acc[j].y = fmaf(ww, v.y, acc[j].y);
      acc[j].z = fmaf(ww, v.z, acc[j].z);
      acc[j].w = fmaf(ww, v.w, acc[j].w);
    }
  }
#pragma unroll
  for (int j = 0; j < CW; ++j) {
    float4 v = acc[j];
    if (ACT == 2) {
      v.x = 1.f / (1.f + expf(-v.x));
      v.y = 1.f / (1.f + expf(-v.y));
      v.z = 1.f / (1.f + expf(-v.z));
      v.w = 1.f / (1.f + expf(-v.w));
    }
    outp[(long)(co0 + j) * HW4] = v;
  }
}

// ---------------- conv 3x3 s1 p1, 128->128, +bias ---------------------------
// IMODE: 0 = raw input; 1 = bn+relu fused on staged input; 2 = input is
// enc_in(x) computed on the fly (1x1 conv 3->128).
// Tile: 64x32 spatial, 8 out-ch per block, 8 px/thread. CI_T=4, LDS 37.4 KB.
template<int IMODE>
__global__ __launch_bounds__(256) void conv3x3_kernel(
    const float* __restrict__ in, const float* __restrict__ w,
    const float* __restrict__ bias, float* __restrict__ out,
    int H, int W, const float2* __restrict__ mr,
    const float* __restrict__ xin, const float* __restrict__ w1,
    const float* __restrict__ b1) {
  constexpr int C = 128, CI_T = 4, CO_T = 8;
  __shared__ float s_in[CI_T][34][66];
  __shared__ float s_w[CO_T][CI_T][12];           // 9 taps padded to 12
  int tid = threadIdx.x;
  int tilesX = W >> 6;
  int tx0 = (blockIdx.x % tilesX) << 6;
  int ty0 = (blockIdx.x / tilesX) << 5;
  int co0 = blockIdx.y * CO_T;
  int n = blockIdx.z;
  int ty = tid >> 3, txg = (tid & 7) << 3;        // row 0..31, col 0,8,..56
  float acc[CO_T][8];
#pragma unroll
  for (int a = 0; a < CO_T; ++a)
#pragma unroll
    for (int s = 0; s < 8; ++s) acc[a][s] = 0.f;
  const long HWl = (long)H * W;
  const long ibase = (long)n * C * HWl;
  for (int ci0 = 0; ci0 < C; ci0 += CI_T) {
    for (int l = tid; l < CI_T * 34 * 66; l += 256) {
      int ci = l / (34 * 66), rem = l % (34 * 66);
      int yy = rem / 66, xx = rem % 66;
      int gy = ty0 + yy - 1, gx = tx0 + xx - 1;
      float v = 0.f;
      if ((unsigned)gy < (unsigned)H && (unsigned)gx < (unsigned)W) {
        if (IMODE == 2) {
          int c = ci0 + ci;
          const float* xp = xin + (long)n * 3 * HWl + (long)gy * W + gx;
          v = b1[c];
          v = fmaf(w1[c * 3 + 0], xp[0], v);
          v = fmaf(w1[c * 3 + 1], xp[HWl], v);
          v = fmaf(w1[c * 3 + 2], xp[2 * HWl], v);
        } else {
          v = in[ibase + (long)(ci0 + ci) * HWl + (long)gy * W + gx];
          if (IMODE == 1) {
            float2 s = mr[ci0 + ci];
            v = fmaxf((v - s.x) * s.y, 0.f);
          }
        }
      }
      s_in[ci][yy][xx] = v;
    }
    for (int l = tid; l < CO_T * CI_T * 9; l += 256) {
      int co = l / (CI_T * 9), rem = l % (CI_T * 9);
      int ci = rem / 9, k = rem % 9;
      s_w[co][ci][k] = w[((long)(co0 + co) * C + ci0 + ci) * 9 + k];
    }
    __syncthreads();
#pragma unroll
    for (int ci = 0; ci < CI_T; ++ci) {
      float r[3][10];
#pragma unroll
      for (int dy = 0; dy < 3; ++dy)
#pragma unroll
        for (int dx = 0; dx < 10; ++dx)
          r[dy][dx] = s_in[ci][ty + dy][txg + dx];
#pragma unroll
      for (int co = 0; co < CO_T; ++co) {
        const float* wp = s_w[co][ci];
        float4 w0 = *(const float4*)wp;
        float4 w4 = *(const float4*)(wp + 4);
        float w8 = wp[8];
#pragma unroll
        for (int sp = 0; sp < 8; ++sp) {
          float a = acc[co][sp];
          a = fmaf(w0.x, r[0][sp], a);
          a = fmaf(w0.y, r[0][sp + 1], a);
          a = fmaf(w0.z, r[0][sp + 2], a);
          a = fmaf(w0.w, r[1][sp], a);
          a = fmaf(w4.x, r[1][sp + 1], a);
          a = fmaf(w4.y, r[1][sp + 2], a);
          a = fmaf(w4.z, r[2][sp], a);
          a = fmaf(w4.w, r[2][sp + 1], a);
          a = fmaf(w8,   r[2][sp + 2], a);
          acc[co][sp] = a;
        }
      }
    }
    __syncthreads();
  }
  int oy = ty0 + ty, ox = tx0 + txg;
#pragma unroll
  for (int co = 0; co < CO_T; ++co) {
    float bb = bias[co0 + co];
    long rowoff = ibase + ((long)(co0 + co) * H + oy) * W + ox;
    float4 v0 = make_float4(acc[co][0] + bb, acc[co][1] + bb, acc[co][2] + bb, acc[co][3] + bb);
    float4 v1 = make_float4(acc[co][4] + bb, acc[co][5] + bb, acc[co][6] + bb, acc[co][7] + bb);
    *(float4*)(out + rowoff) = v0;
    *(float4*)(out + rowoff + 4) = v1;
  }
}

// ---------------- conv 4x4 s2 p1, 128->128, +bias +relu (R2-proven) ---------
__global__ __launch_bounds__(256) void conv4x4s2_kernel(
    const float* __restrict__ in, const float* __restrict__ w,
    const float* __restrict__ bias, float* __restrict__ out,
    int Hin, int Win) {
  constexpr int C = 128, CI_T = 2, CO_T = 16;
  int Hout = Hin >> 1, Wout = Win >> 1;
  __shared__ float s_in[CI_T][34][130];
  __shared__ float s_w[CO_T][CI_T][16];
  int tid = threadIdx.x;
  int tilesX = Wout >> 6;
  int oy0 = (blockIdx.x / tilesX) << 4;
  int ox0 = (blockIdx.x % tilesX) << 6;
  int co0 = blockIdx.y * CO_T;
  int n = blockIdx.z;
  int ty = tid >> 4, txg = tid & 15;
  float acc[CO_T][4];
#pragma unroll
  for (int a = 0; a < CO_T; ++a) acc[a][0] = acc[a][1] = acc[a][2] = acc[a][3] = 0.f;
  const long ibase = (long)n * C * Hin * Win;
  int iy0 = 2 * oy0 - 1, ix0 = 2 * ox0 - 1;
  for (int ci0 = 0; ci0 < C; ci0 += CI_T) {
    for (int l = tid; l < CI_T * 34 * 130; l += 256) {
      int ci = l / (34 * 130), rem = l % (34 * 130);
      int yy = rem / 130, xx = rem % 130;
      int gy = iy0 + yy, gx = ix0 + xx;
      float v = 0.f;
      if ((unsigned)gy < (unsigned)Hin && (unsigned)gx < (unsigned)Win)
        v = in[ibase + ((long)(ci0 + ci) * Hin + gy) * Win + gx];
      s_in[ci][yy][xx] = v;
    }
    for (int l = tid; l < CO_T * CI_T * 16; l += 256) {
      int co = l >> 5, rem = l & 31, ci = rem >> 4, k = rem & 15;
      s_w[co][ci][k] = w[((long)(co0 + co) * C + ci0 + ci) * 16 + k];
    }
    __syncthreads();
#pragma unroll
    for (int ci = 0; ci < CI_T; ++ci) {
      float r[4][10];
      int yb = ty << 1, xb = txg << 3;
#pragma unroll
      for (int dy = 0; dy < 4; ++dy)
#pragma unroll
        for (int dx = 0; dx < 10; ++dx)
          r[dy][dx] = s_in[ci][yb + dy][xb + dx];
#pragma unroll
      for (int co = 0; co < CO_T; ++co) {
        const float* wp = s_w[co][ci];
        float4 w0 = *(const float4*)wp;
        float4 w1 = *(const float4*)(wp + 4);
        float4 w2 = *(const float4*)(wp + 8);
        float4 w3 = *(const float4*)(wp + 12);
#pragma unroll
        for (int sp = 0; sp < 4; ++sp) {
          int xo = sp << 1;
          float a = acc[co][sp];
          a = fmaf(w0.x, r[0][xo], a);     a = fmaf(w0.y, r[0][xo + 1], a);
          a = fmaf(w0.z, r[0][xo + 2], a); a = fmaf(w0.w, r[0][xo + 3], a);
          a = fmaf(w1.x, r[1][xo], a);     a = fmaf(w1.y, r[1][xo + 1], a);
          a = fmaf(w1.z, r[1][xo + 2], a); a = fmaf(w1.w, r[1][xo + 3], a);
          a = fmaf(w2.x, r[2][xo], a);     a = fmaf(w2.y, r[2][xo + 1], a);
          a = fmaf(w2.z, r[2][xo + 2], a); a = fmaf(w2.w, r[2][xo + 3], a);
          a = fmaf(w3.x, r[3][xo], a);     a = fmaf(w3.y, r[3][xo + 1], a);
          a = fmaf(w3.z, r[3][xo + 2], a); a = fmaf(w3.w, r[3][xo + 3], a);
          acc[co][sp] = a;
        }
      }
    }
    __syncthreads();
  }
  const long obase = (long)n * C * Hout * Wout;
  int oy = oy0 + ty, oxb = ox0 + (txg << 2);
#pragma unroll
  for (int co = 0; co < CO_T; ++co) {
    float bb = bias[co0 + co];
    float4 v = make_float4(fmaxf(acc[co][0] + bb, 0.f), fmaxf(acc[co][1] + bb, 0.f),
                           fmaxf(acc[co][2] + bb, 0.f), fmaxf(acc[co][3] + bb, 0.f));
    *(float4*)(out + obase + ((long)(co0 + co) * Hout + oy) * Wout + oxb) = v;
  }
}

// ---------------- ConvTranspose2d(k=4,s=2,p=1), torch w (I,O,4,4), +relu ----
__global__ __launch_bounds__(256) void convT4x4_kernel(
    const float* __restrict__ in, const float* __restrict__ w,
    const float* __restrict__ bias, float* __restrict__ out,
    int Hin, int Win) {
  constexpr int C = 128, CI_T = 4, CO_T = 16;
  int Hout = Hin << 1, Wout = Win << 1;
  __shared__ float s_in[CI_T][18][66];
  __shared__ float s_w[CO_T][CI_T][4];
  int tid = threadIdx.x;
  int cls = blockIdx.z & 3, n = blockIdx.z >> 2;
  int py = cls >> 1, px = cls & 1;
  int tilesX = Win >> 6;
  int m0 = (blockIdx.x / tilesX) << 4;
  int x0 = (blockIdx.x % tilesX) << 6;
  int co0 = blockIdx.y * CO_T;
  int ty = tid >> 4, txg = tid & 15;
  int ky0 = py ? 0 : 1, ky1 = py ? 2 : 3;
  int dy0 = py ? 1 : 0, dy1 = py ? 0 : -1;
  int kx0 = px ? 0 : 1, kx1 = px ? 2 : 3;
  int dxA = px ? 1 : 0, dxB = px ? 0 : -1;
  float acc[CO_T][4];
#pragma unroll
  for (int a = 0; a < CO_T; ++a) acc[a][0] = acc[a][1] = acc[a][2] = acc[a][3] = 0.f;
  const long ibase = (long)n * C * Hin * Win;
  for (int ci0 = 0; ci0 < C; ci0 += CI_T) {
    for (int l = tid; l < CI_T * 18 * 66; l += 256) {
      int ci = l / (18 * 66), rem = l % (18 * 66);
      int yy = rem / 66, xx = rem % 66;
      int gy = m0 - 1 + yy, gx = x0 - 1 + xx;
      float v = 0.f;
      if ((unsigned)gy < (unsigned)Hin && (unsigned)gx < (unsigned)Win)
        v = in[ibase + ((long)(ci0 + ci) * Hin + gy) * Win + gx];
      s_in[ci][yy][xx] = v;
    }
    {
      int l = tid;  // CO_T*CI_T*4 == 256 exactly
      int co = l >> 4, rem = l & 15, ci = rem >> 2, j = rem & 3;
      int ky = (j & 2) ? ky1 : ky0;
      int kx = (j & 1) ? kx1 : kx0;
      s_w[co][ci][j] = w[((long)(ci0 + ci) * C + (co0 + co)) * 16 + ky * 4 + kx];
    }
    __syncthreads();
#pragma unroll
    for (int ci = 0; ci < CI_T; ++ci) {
      float r0v[6], r1v[6];
#pragma unroll
      for (int c2 = 0; c2 < 6; ++c2) {
        r0v[c2] = s_in[ci][ty + 1 + dy0][txg * 4 + c2];
        r1v[c2] = s_in[ci][ty + 1 + dy1][txg * 4 + c2];
      }
#pragma unroll
      for (int co = 0; co < CO_T; ++co) {
        float4 wv = *(const float4*)s_w[co][ci];
#pragma unroll
        for (int sp = 0; sp < 4; ++sp) {
          float a = acc[co][sp];
          a = fmaf(wv.x, r0v[sp + 1 + dxA], a);
          a = fmaf(wv.y, r0v[sp + 1 + dxB], a);
          a = fmaf(wv.z, r1v[sp + 1 + dxA], a);
          a = fmaf(wv.w, r1v[sp + 1 + dxB], a);
          acc[co][sp] = a;
        }
      }
    }
    __syncthreads();
  }
  const long obase = (long)n * C * Hout * Wout;
  int oy = ((m0 + ty) << 1) + py;
#pragma unroll
  for (int co = 0; co < CO_T; ++co) {
    float bb = bias[co0 + co];
    long rowoff = obase + ((long)(co0 + co) * Hout + oy) * Wout;
#pragma unroll
    for (int sp = 0; sp < 4; ++sp) {
      int ox = ((x0 + txg * 4 + sp) << 1) + px;
      out[rowoff + ox] = fmaxf(acc[co][sp] + bb, 0.f);
    }
  }
}

// ---------------- BN batch stats: mean + rsqrt(var+eps) ---------------------
__global__ __launch_bounds__(256) void bn_stats_kernel(
    const float* __restrict__ x, float2* __restrict__ mr, int N, int C, int HW) {
  int c = blockIdx.x;
  double s = 0.0, ss = 0.0;
  int HW4 = HW >> 2;
  for (int n = 0; n < N; ++n) {
    const float4* xp = (const float4*)(x + ((long)n * C + c) * HW);
    for (int i = threadIdx.x; i < HW4; i += 256) {
      float4 v = xp[i];
      s  += (double)v.x + (double)v.y + (double)v.z + (double)v.w;
      ss += (double)v.x * v.x + (double)v.y * v.y + (double)v.z * v.z + (double)v.w * v.w;
    }
  }
  __shared__ double sh_s[256], sh_ss[256];
  sh_s[threadIdx.x] = s; sh_ss[threadIdx.x] = ss;
  __syncthreads();
  for (int off = 128; off > 0; off >>= 1) {
    if (threadIdx.x < off) { sh_s[threadIdx.x] += sh_s[threadIdx.x + off];
                             sh_ss[threadIdx.x] += sh_ss[threadIdx.x + off]; }
    __syncthreads();
  }
  if (threadIdx.x == 0) {
    double cnt = (double)N * HW;
    double m = sh_s[0] / cnt;
    double var = sh_ss[0] / cnt - m * m;
    mr[c] = make_float2((float)m, (float)(1.0 / sqrt(var + 1e-5)));
  }
}

// ---------------- in-place: y = relu(bn(y) + residual) ----------------------
template<int RMODE>
__global__ __launch_bounds__(256) void bn_res_relu_kernel(
    float* __restrict__ y, const float2* __restrict__ mr,
    const float* __restrict__ res,
    const float* __restrict__ xin, const float* __restrict__ w1,
    const float* __restrict__ b1, int HW4) {
  int nc = blockIdx.y;
  int c = nc & 127, n = nc >> 7;
  float2 s = mr[c];
  int i = blockIdx.x * blockDim.x + threadIdx.x;
  if (i >= HW4) return;
  long off = (long)nc * HW4 + i;
  float4 v = ((const float4*)y)[off];
  v.x = (v.x - s.x) * s.y; v.y = (v.y - s.x) * s.y;
  v.z = (v.z - s.x) * s.y; v.w = (v.w - s.x) * s.y;
  float4 r4;
  if (RMODE == 0) {
    r4 = ((const float4*)res)[off];
  } else {
    const float4* xp = (const float4*)(xin) + (long)n * 3 * HW4 + i;
    float4 x0 = xp[0], x1 = xp[HW4], x2 = xp[2 * HW4];
    float wa = w1[c * 3 + 0], wb = w1[c * 3 + 1], wc = w1[c * 3 + 2], bb = b1[c];
    r4.x = fmaf(wa, x0.x, fmaf(wb, x1.x, fmaf(wc, x2.x, bb)));
    r4.y = fmaf(wa, x0.y, fmaf(wb, x1.y, fmaf(wc, x2.y, bb)));
    r4.z = fmaf(wa, x0.z, fmaf(wb, x1.z, fmaf(wc, x2.z, bb)));
    r4.w = fmaf(wa, x0.w, fmaf(wb, x1.w, fmaf(wc, x2.w, bb)));
  }
  v.x = fmaxf(v.x + r4.x, 0.f); v.y = fmaxf(v.y + r4.y, 0.f);
  v.z = fmaxf(v.z + r4.z, 0.f); v.w = fmaxf(v.w + r4.w, 0.f);
  ((float4*)y)[off] = v;
}

// ---------------- VQ: argmin_k ||z - e_k||^2, idx + histogram ---------------
__global__ __launch_bounds__(256) void vq_kernel(
    const float* __restrict__ z, const float* __restrict__ cb,
    float* __restrict__ idx_out, float* __restrict__ counts, int HWl) {
  __shared__ float s_z[64][65];
  __shared__ float s_cb[64][64];
  __shared__ float s_bd[4][64];
  __shared__ int   s_bk[4][64];
  int tid = threadIdx.x;
  int r0 = blockIdx.x * 64;
  for (int l = tid; l < 64 * 64; l += 256) {
    int c = l >> 6, rs = l & 63;
    int r = r0 + rs;
    int n = r / HWl, rem = r % HWl;
    s_z[rs][c] = z[((long)(n * 64 + c)) * HWl + rem];
  }
  int row = tid & 63, cg = tid >> 6;
  float best = 3.4e38f; int bestk = 0;
  for (int k0 = 0; k0 < 1024; k0 += 64) {
    __syncthreads();
    for (int l = tid; l < 4096; l += 256)
      s_cb[l >> 6][l & 63] = cb[(long)(k0 + (l >> 6)) * 64 + (l & 63)];
    __syncthreads();
#pragma unroll
    for (int j = 0; j < 16; ++j) {
      int kk = cg * 16 + j;
      const float* zp = s_z[row];
      const float* cp = s_cb[kk];
      float d = 0.f;
#pragma unroll
      for (int c = 0; c < 64; ++c) {
        float t = zp[c] - cp[c];
        d = fmaf(t, t, d);
      }
      int k = k0 + kk;
      if (d < best) { best = d; bestk = k; }
    }
  }
  s_bd[cg][row] = best; s_bk[cg][row] = bestk;
  __syncthreads();
  if (tid < 64) {
    float bd = s_bd[0][tid]; int bk = s_bk[0][tid];
#pragma unroll
    for (int g = 1; g < 4; ++g) {
      float d2 = s_bd[g][tid]; int k2 = s_bk[g][tid];
      if (d2 < bd || (d2 == bd && k2 < bk)) { bd = d2; bk = k2; }
    }
    idx_out[r0 + tid] = (float)bk;
    atomicAdd(&counts[bk], 1.0f);
  }
}

// ---------------- zero small buffer ----------------------------------------
__global__ __launch_bounds__(256) void zero_kernel(float* __restrict__ p, int n) {
  int i = blockIdx.x * 256 + threadIdx.x;
  if (i < n) p[i] = 0.f;
}

// ---------------- loss = sum p log p  (= -entropy) --------------------------
__global__ __launch_bounds__(256) void entropy_kernel(
    const float* __restrict__ counts, float* __restrict__ loss_out) {
  __shared__ double sh[256];
  int tid = threadIdx.x;
  double s = 0.0;
  for (int i = tid; i < 1024; i += 256) s += (double)counts[i] + 1e-6;
  sh[tid] = s; __syncthreads();
  for (int off = 128; off > 0; off >>= 1) {
    if (tid < off) sh[tid] += sh[tid + off];
    __syncthreads();
  }
  double S = sh[0];
  __syncthreads();
  double pl = 0.0;
  for (int i = tid; i < 1024; i += 256) {
    double p = ((double)counts[i] + 1e-6) / S;
    pl += p * log(p);
  }
  sh[tid] = pl; __syncthreads();
  for (int off = 128; off > 0; off >>= 1) {
    if (tid < off) sh[tid] += sh[tid + off];
    __syncthreads();
  }
  if (tid == 0) loss_out[0] = (float)sh[0];
}

// ---------------------------------------------------------------------------
extern "C" void kernel_launch(void* const* d_in, const int* in_sizes, int n_in,
                              void* d_out, int out_size, void* d_ws, size_t ws_size,
                              hipStream_t stream) {
  (void)in_sizes; (void)n_in; (void)out_size; (void)ws_size;
  const float* x          = (const float*)d_in[0];
  const float* enc_in_w   = (const float*)d_in[1];
  const float* enc_in_b   = (const float*)d_in[2];
  const float* enc_res_w1 = (const float*)d_in[3];
  const float* enc_res_b1 = (const float*)d_in[4];
  const float* enc_res_w2 = (const float*)d_in[5];
  const float* enc_res_b2 = (const float*)d_in[6];
  const float* enc_down_w = (const float*)d_in[7];
  const float* enc_down_b = (const float*)d_in[8];
  const float* enc_out_w  = (const float*)d_in[9];
  const float* enc_out_b  = (const float*)d_in[10];
  const float* dec_in_w   = (const float*)d_in[11];
  const float* dec_in_b   = (const float*)d_in[12];
  const float* dec_res_w1 = (const float*)d_in[13];
  const float* dec_res_b1 = (const float*)d_in[14];
  const float* dec_res_w2 = (const float*)d_in[15];
  const float* dec_res_b2 = (const float*)d_in[16];
  const float* dec_up_w   = (const float*)d_in[17];
  const float* dec_up_b   = (const float*)d_in[18];
  const float* dec_out_w  = (const float*)d_in[19];
  const float* dec_out_b  = (const float*)d_in[20];
  const float* codebook   = (const float*)d_in[21];
  float* out = (float*)d_out;

  // Workspace: EXACTLY two 128-MiB fp32 buffers.
  const long BIG = 33554432;
  const long S1 = 8388608, S2 = 16777216, S3 = 25165824;
  float* P0 = (float*)d_ws;
  float* P1 = P0 + BIG;
  // Small scratch in d_out[0:1280) — recon overwrites it at the end.
  float2* mr  = (float2*)out;
  float* hist = out + 256;

  const int W3 = 128 * 128 * 9, W4 = 128 * 128 * 16, BS = 128;

  // conv3x3 grids: (W/64)*(H/32) tiles, 16 co-blocks, 4 batch
  const dim3 g256(32, 16, 4), g128(8, 16, 4), g64(2, 16, 4);

  // ===================== encoder =====================
  conv3x3_kernel<2><<<g256, 256, 0, stream>>>(
      nullptr, enc_res_w1, enc_res_b1, P0, 256, 256, nullptr, x, enc_in_w, enc_in_b);
  bn_stats_kernel<<<128, 256, 0, stream>>>(P0, mr, 4, 128, 65536);
  conv3x3_kernel<1><<<g256, 256, 0, stream>>>(
      P0, enc_res_w2, enc_res_b2, P1, 256, 256, mr, nullptr, nullptr, nullptr);
  bn_stats_kernel<<<128, 256, 0, stream>>>(P1, mr, 4, 128, 65536);
  bn_res_relu_kernel<1><<<dim3(64, 512), 256, 0, stream>>>(
      P1, mr, nullptr, x, enc_in_w, enc_in_b, 16384);
  conv4x4s2_kernel<<<dim3(16, 8, 4), 256, 0, stream>>>(P1, enc_down_w, enc_down_b, P0, 256, 256);

  conv3x3_kernel<0><<<g128, 256, 0, stream>>>(
      P0, enc_res_w1 + W3, enc_res_b1 + BS, P0 + S1, 128, 128, nullptr, nullptr, nullptr, nullptr);
  bn_stats_kernel<<<128, 256, 0, stream>>>(P0 + S1, mr, 4, 128, 16384);
  conv3x3_kernel<1><<<g128, 256, 0, stream>>>(
      P0 + S1, enc_res_w2 + W3, enc_res_b2 + BS, P0 + S2, 128, 128, mr, nullptr, nullptr, nullptr);
  bn_stats_kernel<<<128, 256, 0, stream>>>(P0 + S2, mr, 4, 128, 16384);
  bn_res_relu_kernel<0><<<dim3(16, 512), 256, 0, stream>>>(
      P0 + S2, mr, P0, nullptr, nullptr, nullptr, 4096);
  conv4x4s2_kernel<<<dim3(4, 8, 4), 256, 0, stream>>>(
      P0 + S2, enc_down_w + W4, enc_down_b + BS, P0 + S3, 128, 128);

  conv1x1_kernel<0, 16><<<dim3(16, 4), 256, 16 * 128 * 4, stream>>>(
      P0 + S3, enc_out_w, enc_out_b, P1, 4, 128, 64, 4096);

  // ===================== VQ =====================
  zero_kernel<<<4, 256, 0, stream>>>(hist, 1024);
  vq_kernel<<<256, 256, 0, stream>>>(P1, codebook, out + RE_SIZE + 1, hist, 4096);
  entropy_kernel<<<1, 256, 0, stream>>>(hist, out + RE_SIZE);

  // ===================== decoder =====================
  conv1x1_kernel<0, 16><<<dim3(16, 8), 256, 16 * 64 * 4, stream>>>(
      P1, dec_in_w, dec_in_b, P0, 4, 64, 128, 4096);

  conv3x3_kernel<0><<<g64, 256, 0, stream>>>(
      P0, dec_res_w1, dec_res_b1, P0 + S1, 64, 64, nullptr, nullptr, nullptr, nullptr);
  bn_stats_kernel<<<128, 256, 0, stream>>>(P0 + S1, mr, 4, 128, 4096);
  conv3x3_kernel<1><<<g64, 256, 0, stream>>>(
      P0 + S1, dec_res_w2, dec_res_b2, P0 + S2, 64, 64, mr, nullptr, nullptr, nullptr);
  bn_stats_kernel<<<128, 256, 0, stream>>>(P0 + S2, mr, 4, 128, 4096);
  bn_res_relu_kernel<0><<<dim3(4, 512), 256, 0, stream>>>(
      P0 + S2, mr, P0, nullptr, nullptr, nullptr, 1024);
  convT4x4_kernel<<<dim3(4, 8, 16), 256, 0, stream>>>(P0 + S2, dec_up_w, dec_up_b, P0 + S3, 64, 64);

  conv3x3_kernel<0><<<g128, 256, 0, stream>>>(
      P0 + S3, dec_res_w1 + W3, dec_res_b1 + BS, P1, 128, 128, nullptr, nullptr, nullptr, nullptr);
  bn_stats_kernel<<<128, 256, 0, stream>>>(P1, mr, 4, 128, 16384);
  conv3x3_kernel<1><<<g128, 256, 0, stream>>>(
      P1, dec_res_w2 + W3, dec_res_b2 + BS, P1 + S1, 128, 128, mr, nullptr, nullptr, nullptr);
  bn_stats_kernel<<<128, 256, 0, stream>>>(P1 + S1, mr, 4, 128, 16384);
  bn_res_relu_kernel<0><<<dim3(16, 512), 256, 0, stream>>>(
      P1 + S1, mr, P0 + S3, nullptr, nullptr, nullptr, 4096);
  convT4x4_kernel<<<dim3(16, 8, 16), 256, 0, stream>>>(
      P1 + S1, dec_up_w + W4, dec_up_b + BS, P0, 128, 128);

  conv1x1_kernel<2, 3><<<dim3(256, 1), 256, 3 * 128 * 4, stream>>>(
      P0, dec_out_w, dec_out_b, out, 4, 128, 3, 65536);
}